// Round 1
// baseline (4335.991 us; speedup 1.0000x reference)
//
#include <hip/hip_runtime.h>
#include <cstdint>
#include <cstddef>

// Problem constants (from reference)
#define NN    100000
#define CCH   256
#define EMB   256
#define OUTD  8
#define HIDD  256
#define NHEADS 4
#define KKP   20000
#define RR    16
#define EE    800000
#define KRR   (KKP*RR)   // 320000

// ---------------------------------------------------------------------------
// Generic fp32 GEMM: C[M,256] = act(A[M,Ka] @ B[Ka,256] (+extras) + bias)
// Tile 128x128, BK=8, 256 threads, 8x8 microtile.
// EPI: 0=none 1=relu 2=sigmoid 3=relu + retrieval-extra (o_retr/score rows of rp_W1)
// ---------------------------------------------------------------------------
enum { EPI_NONE = 0, EPI_RELU = 1, EPI_SIGMOID = 2, EPI_RELU_RETR = 3 };

template <int EPI>
__launch_bounds__(256)
__global__ void gemm_k(const float* __restrict__ A, int M, int Ka,
                       const float* __restrict__ B, int ldb,
                       const float* __restrict__ bias,
                       float* __restrict__ C,
                       const float* __restrict__ o_ex,
                       const float* __restrict__ s_ex,
                       const float* __restrict__ Wex)
{
    const int N = 256;
    __shared__ float As[8][128];   // transposed A tile
    __shared__ float Bs[8][128];
    const int row0 = blockIdx.x * 128;
    const int col0 = blockIdx.y * 128;
    const int t  = threadIdx.x;
    const int tx = t & 15, ty = t >> 4;

    const int arow = t >> 1;          // 0..127
    const int ak   = (t & 1) * 4;     // 0 or 4
    const int brow = t >> 5;          // 0..7
    const int bcol = (t & 31) * 4;    // 0..124
    const bool a_ok = (row0 + arow) < M;
    const float* Ag = A + (size_t)(row0 + arow) * Ka + ak;
    const float* Bg = B + (size_t)brow * ldb + col0 + bcol;

    float acc[8][8];
#pragma unroll
    for (int i = 0; i < 8; i++)
#pragma unroll
        for (int j = 0; j < 8; j++) acc[i][j] = 0.f;

    for (int kk = 0; kk < Ka; kk += 8) {
        float4 av = make_float4(0.f, 0.f, 0.f, 0.f);
        if (a_ok) av = *(const float4*)(Ag + kk);
        float4 bv = *(const float4*)(Bg + (size_t)kk * ldb);
        __syncthreads();
        As[ak + 0][arow] = av.x; As[ak + 1][arow] = av.y;
        As[ak + 2][arow] = av.z; As[ak + 3][arow] = av.w;
        *(float4*)&Bs[brow][bcol] = bv;
        __syncthreads();
#pragma unroll
        for (int k2 = 0; k2 < 8; k2++) {
            float a[8], b[8];
            *(float4*)(a)     = *(const float4*)&As[k2][ty * 8];
            *(float4*)(a + 4) = *(const float4*)&As[k2][ty * 8 + 4];
            *(float4*)(b)     = *(const float4*)&Bs[k2][tx * 8];
            *(float4*)(b + 4) = *(const float4*)&Bs[k2][tx * 8 + 4];
#pragma unroll
            for (int i = 0; i < 8; i++)
#pragma unroll
                for (int j = 0; j < 8; j++)
                    acc[i][j] = fmaf(a[i], b[j], acc[i][j]);
        }
    }

    float bv8[8];
#pragma unroll
    for (int j = 0; j < 8; j++) bv8[j] = bias[col0 + tx * 8 + j];

#pragma unroll
    for (int i = 0; i < 8; i++) {
        int r = row0 + ty * 8 + i;
        if (r >= M) continue;
        float v[8];
#pragma unroll
        for (int j = 0; j < 8; j++) v[j] = acc[i][j] + bv8[j];
        if (EPI == EPI_RELU_RETR) {
            // extra K-rows of rp_W1: rows 256..263 (o_retr), row 264 (score)
            float ov[8];
#pragma unroll
            for (int u = 0; u < 8; u++) ov[u] = o_ex[(size_t)r * 8 + u];
            float sv = s_ex[r];
#pragma unroll
            for (int j = 0; j < 8; j++) {
                int c = col0 + tx * 8 + j;
                float e = sv * Wex[8 * 256 + c];
#pragma unroll
                for (int u = 0; u < 8; u++) e = fmaf(ov[u], Wex[u * 256 + c], e);
                v[j] += e;
            }
        }
#pragma unroll
        for (int j = 0; j < 8; j++) {
            if (EPI == EPI_RELU || EPI == EPI_RELU_RETR) v[j] = fmaxf(v[j], 0.f);
            if (EPI == EPI_SIGMOID) v[j] = 1.f / (1.f + expf(-v[j]));
        }
        float* Cp = C + (size_t)r * N + col0 + tx * 8;
        *(float4*)Cp       = make_float4(v[0], v[1], v[2], v[3]);
        *(float4*)(Cp + 4) = make_float4(v[4], v[5], v[6], v[7]);
    }
}

// ---------------------------------------------------------------------------
// Small helper kernels
// ---------------------------------------------------------------------------
__global__ void gather_hq_k(const float* __restrict__ hc, const int* __restrict__ nids,
                            float* __restrict__ hq)
{
    int t = threadIdx.x;
    int k = blockIdx.x * 4 + (t >> 6);
    int c = t & 63;
    if (k < KKP) {
        int nid = nids[k];
        ((float4*)hq)[(size_t)k * 64 + c] = ((const float4*)hc)[(size_t)nid * 64 + c];
    }
}

__global__ void concat_k(const float* __restrict__ hq, const float* __restrict__ rctx,
                         float* __restrict__ acat)
{
    int gid = blockIdx.x * 256 + threadIdx.x;   // over K*128 float4s
    if (gid >= KKP * 128) return;
    int k = gid >> 7, c = gid & 127;
    float4 v;
    if (c < 64) v = ((const float4*)hq)[(size_t)k * 64 + c];
    else        v = ((const float4*)rctx)[(size_t)k * 64 + (c - 64)];
    ((float4*)acat)[gid] = v;
}

// attention scores + softmax over R.  One block per k; wave h = head h.
__launch_bounds__(256)
__global__ void att_scores_k(const float* __restrict__ qh, const float* __restrict__ kh,
                             float* __restrict__ att)
{
    int k = blockIdx.x;
    int t = threadIdx.x;
    int lane = t & 63;
    float qv = qh[(size_t)k * 256 + t];
    const float* khp = kh + (size_t)k * (RR * 256);
    float myscore = -1e30f;
    for (int r = 0; r < RR; r++) {
        float p = qv * khp[r * 256 + t];
#pragma unroll
        for (int off = 1; off < 64; off <<= 1) p += __shfl_xor(p, off);
        if (lane == r) myscore = p * 0.125f;   // 1/sqrt(64)
    }
    float m = (lane < RR) ? myscore : -1e30f;
#pragma unroll
    for (int off = 1; off < 16; off <<= 1) m = fmaxf(m, __shfl_xor(m, off));
    float pe = (lane < RR) ? expf(myscore - m) : 0.f;
    float ssum = pe;
#pragma unroll
    for (int off = 1; off < 16; off <<= 1) ssum += __shfl_xor(ssum, off);
    if (lane < RR) att[(size_t)k * 64 + (t >> 6) * 16 + lane] = pe / ssum;
}

__launch_bounds__(256)
__global__ void att_apply_k(const float* __restrict__ att, const float* __restrict__ vh,
                            float* __restrict__ ctx)
{
    int k = blockIdx.x;
    int t = threadIdx.x;
    int h = t >> 6;
    __shared__ float a_s[64];
    if (t < 64) a_s[t] = att[(size_t)k * 64 + t];
    __syncthreads();
    const float* vp = vh + (size_t)k * (RR * 256) + t;
    float acc = 0.f;
#pragma unroll
    for (int r = 0; r < RR; r++) acc = fmaf(a_s[h * 16 + r], vp[r * 256], acc);
    ctx[(size_t)k * 256 + t] = acc;
}

// winner-resolution for duplicate outpin_nids (numpy last-write-wins == max k)
__global__ void winner_k(const int* __restrict__ nids, int* __restrict__ winner)
{
    int gid = blockIdx.x * 256 + threadIdx.x;
    if (gid < KKP) atomicMax(&winner[nids[gid]], gid);
}

__global__ void scatter_h_k(const int* __restrict__ nids, const int* __restrict__ winner,
                            const float* __restrict__ hq, const float* __restrict__ gate,
                            const float* __restrict__ upd, float* __restrict__ h)
{
    int t = threadIdx.x;
    int k = blockIdx.x * 4 + (t >> 6);
    int c = t & 63;
    if (k >= KKP) return;
    int nid = nids[k];
    if (winner[nid] != k) return;
    float4 hv = ((const float4*)hq)[(size_t)k * 64 + c];
    float4 gv = ((const float4*)gate)[(size_t)k * 64 + c];
    float4 uv = ((const float4*)upd)[(size_t)k * 64 + c];
    float4 r;
    r.x = hv.x + gv.x * uv.x; r.y = hv.y + gv.y * uv.y;
    r.z = hv.z + gv.z * uv.z; r.w = hv.w + gv.w * uv.w;
    ((float4*)h)[(size_t)nid * 64 + c] = r;
}

// ---------------------------------------------------------------------------
// CSR build (per call; same work every call)
// ---------------------------------------------------------------------------
__global__ void edge_count_k(const int* __restrict__ dst, int* __restrict__ cnt, int e)
{
    int gid = blockIdx.x * 256 + threadIdx.x;
    if (gid < e) atomicAdd(&cnt[dst[gid]], 1);
}

__global__ void isd_k(const int* __restrict__ cnt, float* __restrict__ isd, int n)
{
    int gid = blockIdx.x * 256 + threadIdx.x;
    if (gid < n) isd[gid] = rsqrtf((float)(cnt[gid] + 1));   // +1 self loop
}

#define SCANB 1024
__global__ void scan1_k(const int* __restrict__ in, int* __restrict__ out,
                        int* __restrict__ bsums, int n)
{
    __shared__ int s[SCANB];
    int tid = threadIdx.x;
    int gid = blockIdx.x * SCANB + tid;
    int v = (gid < n) ? in[gid] : 0;
    s[tid] = v;
    __syncthreads();
    for (int off = 1; off < SCANB; off <<= 1) {
        int add = (tid >= off) ? s[tid - off] : 0;
        __syncthreads();
        s[tid] += add;
        __syncthreads();
    }
    if (gid < n) out[gid] = s[tid] - v;          // exclusive within block
    if (tid == SCANB - 1) bsums[blockIdx.x] = s[tid];
}

__global__ void scan2_k(int* bsums, int nb)
{
    if (threadIdx.x == 0 && blockIdx.x == 0) {
        int run = 0;
        for (int i = 0; i < nb; i++) { int v = bsums[i]; bsums[i] = run; run += v; }
    }
}

__global__ void scan3_k(int* __restrict__ out, const int* __restrict__ bsums, int n, int total)
{
    int gid = blockIdx.x * SCANB + threadIdx.x;
    if (gid < n) out[gid] += bsums[blockIdx.x];
    if (gid == 0) out[n] = total;
}

__global__ void csr_scatter_k(const int* __restrict__ src, const int* __restrict__ dst,
                              const int* __restrict__ row_start, int* __restrict__ cursor,
                              const float* __restrict__ isd,
                              int* __restrict__ csr_src, float* __restrict__ csr_w, int e)
{
    int gid = blockIdx.x * 256 + threadIdx.x;
    if (gid < e) {
        int sP = src[gid], dP = dst[gid];
        int pos = row_start[dP] + atomicAdd(&cursor[dP], 1);
        csr_src[pos] = sP;
        csr_w[pos] = isd[sP] * isd[dP];
    }
}

// GCN aggregation: out[i] = (relu?)( x[i]/deg[i] + sum_in-edges x[src]*w )
template <int RELU>
__launch_bounds__(256)
__global__ void gnn_agg_k(const float* __restrict__ x, const int* __restrict__ row_start,
                          const int* __restrict__ csr_src, const float* __restrict__ csr_w,
                          const float* __restrict__ isd, float* __restrict__ out)
{
    int i = blockIdx.x;
    int c = threadIdx.x;
    float si = isd[i];
    float acc = x[(size_t)i * 256 + c] * si * si;
    int s0 = row_start[i], s1 = row_start[i + 1];
    for (int j = s0; j < s1; j++) {
        int sP = csr_src[j];
        float w = csr_w[j];
        acc = fmaf(x[(size_t)sP * 256 + c], w, acc);
    }
    if (RELU) acc = fmaxf(acc, 0.f);
    out[(size_t)i * 256 + c] = acc;
}

// head layer-2 + teacher add: out[N,8] = teacher + thid@W2 + b2
__launch_bounds__(256)
__global__ void head_out_k(const float* __restrict__ thid, const float* __restrict__ W2,
                           const float* __restrict__ b2, const float* __restrict__ teacher,
                           float* __restrict__ outp, int n)
{
    __shared__ float ts[32][257];
    __shared__ float w2s[256 * 8];
    int t = threadIdx.x;
    int rbase = blockIdx.x * 32;
    for (int i = t; i < 2048; i += 256) w2s[i] = W2[i];
    for (int i = t; i < 32 * 256; i += 256) {
        int rr = i >> 8, cc = i & 255;
        int gr = rbase + rr;
        ts[rr][cc] = (gr < n) ? thid[(size_t)gr * 256 + cc] : 0.f;
    }
    __syncthreads();
    int rr = t >> 3;
    int cc = t & 7;
    int gr = rbase + rr;
    if (gr >= n) return;
    float acc = b2[cc];
    for (int kk = 0; kk < 256; kk++)
        acc = fmaf(ts[rr][kk], w2s[kk * 8 + cc], acc);
    outp[(size_t)gr * 8 + cc] = teacher[(size_t)gr * 8 + cc] + acc;
}

// ---------------------------------------------------------------------------
// Host launcher
// ---------------------------------------------------------------------------
extern "C" void kernel_launch(void* const* d_in, const int* in_sizes, int n_in,
                              void* d_out, int out_size, void* d_ws, size_t ws_size,
                              hipStream_t stream)
{
    (void)in_sizes; (void)n_in; (void)out_size; (void)ws_size;
    const float* h_cone     = (const float*)d_in[0];
    const float* z_retr     = (const float*)d_in[1];
    const float* o_retr     = (const float*)d_in[2];
    const float* retr_score = (const float*)d_in[3];
    const float* teacher    = (const float*)d_in[4];
    const int*   nids       = (const int*)d_in[5];
    const int*   edge       = (const int*)d_in[6];
    const float* rp_W1 = (const float*)d_in[7];   const float* rp_b1 = (const float*)d_in[8];
    const float* rp_W2 = (const float*)d_in[9];   const float* rp_b2 = (const float*)d_in[10];
    const float* qp_W  = (const float*)d_in[11];  const float* qp_b  = (const float*)d_in[12];
    const float* inW   = (const float*)d_in[13];  const float* inB   = (const float*)d_in[14];
    const float* outW  = (const float*)d_in[15];  const float* outB  = (const float*)d_in[16];
    const float* gW1   = (const float*)d_in[17];  const float* gB1   = (const float*)d_in[18];
    const float* gW2   = (const float*)d_in[19];  const float* gB2   = (const float*)d_in[20];
    const float* uW1   = (const float*)d_in[21];  const float* uB1   = (const float*)d_in[22];
    const float* uW2   = (const float*)d_in[23];  const float* uB2   = (const float*)d_in[24];
    const float* gnW1  = (const float*)d_in[25];  const float* gnB1  = (const float*)d_in[26];
    const float* gnW2  = (const float*)d_in[27];  const float* gnB2  = (const float*)d_in[28];
    const float* hW1   = (const float*)d_in[29];  const float* hB1   = (const float*)d_in[30];
    const float* hW2   = (const float*)d_in[31];  const float* hB2   = (const float*)d_in[32];
    float* out = (float*)d_out;

    // -------- workspace layout (~894 MB peak) --------
    char* ws = (char*)d_ws;
    size_t off = 0;
    auto alloc = [&](size_t bytes) -> void* {
        void* p = ws + off;
        off = (off + bytes + 255) & ~(size_t)255;
        return p;
    };
    float* bufA = (float*)alloc((size_t)KRR * 256 * 4);   // hidden -> kh -> vh
    float* bufB = (float*)alloc((size_t)KRR * 256 * 4);   // kv
    // GNN stage reuses the big region (retrieval buffers dead by then)
    float* h    = bufA;
    float* x1   = bufA + (size_t)1 * NN * 256;
    float* h1   = bufA + (size_t)2 * NN * 256;
    float* x2   = bufA + (size_t)3 * NN * 256;
    float* h2   = bufA + (size_t)4 * NN * 256;
    float* thid = bufA + (size_t)5 * NN * 256;            // 6*102.4MB <= 655MB

    float* hq   = (float*)alloc((size_t)KKP * 256 * 4);
    float* qtmp = (float*)alloc((size_t)KKP * 256 * 4);
    float* qhb  = (float*)alloc((size_t)KKP * 256 * 4);
    float* att  = (float*)alloc((size_t)KKP * 64 * 4);
    float* ctx  = (float*)alloc((size_t)KKP * 256 * 4);
    float* rctx = (float*)alloc((size_t)KKP * 256 * 4);
    float* acat = (float*)alloc((size_t)KKP * 512 * 4);
    float* ghid = (float*)alloc((size_t)KKP * 256 * 4);
    float* gate = (float*)alloc((size_t)KKP * 256 * 4);
    float* uhid = (float*)alloc((size_t)KKP * 256 * 4);
    float* upd  = (float*)alloc((size_t)KKP * 256 * 4);
    int*   winner    = (int*)alloc(NN * 4);
    int*   cnt       = (int*)alloc(NN * 4);
    int*   cursor    = (int*)alloc(NN * 4);
    int*   row_start = (int*)alloc((NN + 1) * 4);
    int*   bsums     = (int*)alloc(1024 * 4);
    float* isd       = (float*)alloc(NN * 4);
    int*   csr_src   = (int*)alloc((size_t)EE * 4);
    float* csr_w     = (float*)alloc((size_t)EE * 4);

    const int* esrc = edge;
    const int* edst = edge + EE;

    auto gemm = [&](int epi, const float* A, int M, int Ka, const float* B, int ldb,
                    const float* bias, float* Cp,
                    const float* o_ex, const float* s_ex, const float* Wex) {
        dim3 grid((M + 127) / 128, 2);
        switch (epi) {
        case EPI_NONE:      gemm_k<EPI_NONE><<<grid, 256, 0, stream>>>(A, M, Ka, B, ldb, bias, Cp, o_ex, s_ex, Wex); break;
        case EPI_RELU:      gemm_k<EPI_RELU><<<grid, 256, 0, stream>>>(A, M, Ka, B, ldb, bias, Cp, o_ex, s_ex, Wex); break;
        case EPI_SIGMOID:   gemm_k<EPI_SIGMOID><<<grid, 256, 0, stream>>>(A, M, Ka, B, ldb, bias, Cp, o_ex, s_ex, Wex); break;
        default:            gemm_k<EPI_RELU_RETR><<<grid, 256, 0, stream>>>(A, M, Ka, B, ldb, bias, Cp, o_ex, s_ex, Wex); break;
        }
    };

    // ---- CSR prep (independent of retrieval stage) ----
    hipMemsetAsync(cnt, 0, NN * 4, stream);
    hipMemsetAsync(cursor, 0, NN * 4, stream);
    edge_count_k<<<(EE + 255) / 256, 256, 0, stream>>>(edst, cnt, EE);
    isd_k<<<(NN + 255) / 256, 256, 0, stream>>>(cnt, isd, NN);
    int nb = (NN + SCANB - 1) / SCANB;   // 98
    scan1_k<<<nb, SCANB, 0, stream>>>(cnt, row_start, bsums, NN);
    scan2_k<<<1, 64, 0, stream>>>(bsums, nb);
    scan3_k<<<nb, SCANB, 0, stream>>>(row_start, bsums, NN, EE);
    csr_scatter_k<<<(EE + 255) / 256, 256, 0, stream>>>(esrc, edst, row_start, cursor, isd,
                                                        csr_src, csr_w, EE);

    // ---- retrieval MLP: hidden(bufA) -> kv(bufB) ----
    gemm(EPI_RELU_RETR, z_retr, KRR, 256, rp_W1, 256, rp_b1, bufA,
         o_retr, retr_score, rp_W1 + 256 * 256);
    gemm(EPI_NONE, bufA, KRR, 256, rp_W2, 256, rp_b2, bufB, nullptr, nullptr, nullptr);
    // kh into bufA
    gemm(EPI_NONE, bufB, KRR, 256, inW + 256, 768, inB + 256, bufA, nullptr, nullptr, nullptr);

    // ---- queries ----
    gather_hq_k<<<(KKP + 3) / 4, 256, 0, stream>>>(h_cone, nids, hq);
    gemm(EPI_NONE, hq, KKP, 256, qp_W, 256, qp_b, qtmp, nullptr, nullptr, nullptr);
    gemm(EPI_NONE, qtmp, KKP, 256, inW, 768, inB, qhb, nullptr, nullptr, nullptr);

    // ---- attention: scores on kh(bufA), then vh overwrites bufA ----
    att_scores_k<<<KKP, 256, 0, stream>>>(qhb, bufA, att);
    gemm(EPI_NONE, bufB, KRR, 256, inW + 512, 768, inB + 512, bufA, nullptr, nullptr, nullptr);
    att_apply_k<<<KKP, 256, 0, stream>>>(att, bufA, ctx);
    gemm(EPI_NONE, ctx, KKP, 256, outW, 256, outB, rctx, nullptr, nullptr, nullptr);

    // ---- gate / update ----
    concat_k<<<(KKP * 128 + 255) / 256, 256, 0, stream>>>(hq, rctx, acat);
    gemm(EPI_RELU, acat, KKP, 512, gW1, 256, gB1, ghid, nullptr, nullptr, nullptr);
    gemm(EPI_SIGMOID, ghid, KKP, 256, gW2, 256, gB2, gate, nullptr, nullptr, nullptr);
    gemm(EPI_RELU, rctx, KKP, 256, uW1, 256, uB1, uhid, nullptr, nullptr, nullptr);
    gemm(EPI_NONE, uhid, KKP, 256, uW2, 256, uB2, upd, nullptr, nullptr, nullptr);

    // ---- scatter back into h (last-write-wins on duplicate nids) ----
    hipMemsetAsync(winner, 0xFF, NN * 4, stream);
    winner_k<<<(KKP + 255) / 256, 256, 0, stream>>>(nids, winner);
    hipMemcpyAsync(h, h_cone, (size_t)NN * 256 * 4, hipMemcpyDeviceToDevice, stream);
    scatter_h_k<<<(KKP + 3) / 4, 256, 0, stream>>>(nids, winner, hq, gate, upd, h);

    // ---- cone GNN (2-layer GCN) ----
    gemm(EPI_NONE, h, NN, 256, gnW1, 256, gnB1, x1, nullptr, nullptr, nullptr);
    gnn_agg_k<1><<<NN, 256, 0, stream>>>(x1, row_start, csr_src, csr_w, isd, h1);
    gemm(EPI_NONE, h1, NN, 256, gnW2, 256, gnB2, x2, nullptr, nullptr, nullptr);
    gnn_agg_k<0><<<NN, 256, 0, stream>>>(x2, row_start, csr_src, csr_w, isd, h2);

    // ---- head ----
    gemm(EPI_RELU, h2, NN, 256, hW1, 256, hB1, thid, nullptr, nullptr, nullptr);
    head_out_k<<<(NN + 31) / 32, 256, 0, stream>>>(thid, hW2, hB2, teacher, out, NN);
}

// Round 2
// 2044.598 us; speedup vs baseline: 2.1207x; 2.1207x over previous
//
#include <hip/hip_runtime.h>
#include <cstdint>
#include <cstddef>

typedef unsigned short u16;

// Problem constants
#define NN    100000
#define OUTD  8
#define KKP   20000
#define RR    16
#define EE    800000
#define KRR   (KKP*RR)   // 320000
#define KP    20096      // 157*128
#define NP    100096     // 782*128
#define KAEXT 288        // 265 padded to 9*32

typedef __bf16 v8bf __attribute__((ext_vector_type(8)));
typedef float  v4f  __attribute__((ext_vector_type(4)));

__device__ __forceinline__ float b2f(u16 u) {
    union { uint32_t i; float f; } v; v.i = (uint32_t)u << 16; return v.f;
}
__device__ __forceinline__ u16 f2b(float f) {
    union { float f; uint32_t i; } v; v.f = f;
    uint32_t i = v.i;
    return (u16)((i + 0x7fffu + ((i >> 16) & 1u)) >> 16);
}

#define GLDS(g, l) __builtin_amdgcn_global_load_lds(                         \
    (const __attribute__((address_space(1))) void*)(g),                      \
    (__attribute__((address_space(3))) void*)(l), 16, 0, 0)

// ---------------------------------------------------------------------------
// bf16 MFMA GEMM: C[M,256] = act(A[M,Ka] @ Wt[256,Ka]^T + bias)
// 128x128 tile, BK=32, 4 waves, 4x4 16x16x32 frags per wave.
// EPI: 0 none, 1 relu, 2 sigmoid.  OMODE: 1 bf16 out (ldcb), 2 f32 out (ld 256)
// ---------------------------------------------------------------------------
template <int EPI, int OMODE>
__launch_bounds__(256)
__global__ void gemm_bf_k(const u16* __restrict__ A, int lda, int M, int Ka,
                          const u16* __restrict__ Wt,
                          const float* __restrict__ bias,
                          u16* __restrict__ Cb, int ldcb,
                          float* __restrict__ Cf)
{
    __shared__ u16 As[128 * 32];
    __shared__ u16 Bs[128 * 32];
    const int row0 = blockIdx.x * 128;
    const int col0 = blockIdx.y * 128;
    const int t    = threadIdx.x;
    const int lane = t & 63;
    const int w    = t >> 6;
    const int wm   = w & 1, wn = w >> 1;

    const int idx0 = t, idx1 = t + 256;
    const u16* Ag0 = A  + (size_t)(row0 + (idx0 >> 2)) * lda + (idx0 & 3) * 8;
    const u16* Ag1 = A  + (size_t)(row0 + (idx1 >> 2)) * lda + (idx1 & 3) * 8;
    const u16* Bg0 = Wt + (size_t)(col0 + (idx0 >> 2)) * Ka  + (idx0 & 3) * 8;
    const u16* Bg1 = Wt + (size_t)(col0 + (idx1 >> 2)) * Ka  + (idx1 & 3) * 8;
    u16* Asp0 = &As[idx0 * 8];
    u16* Asp1 = &As[idx1 * 8];
    u16* Bsp0 = &Bs[idx0 * 8];
    u16* Bsp1 = &Bs[idx1 * 8];

    v4f acc[4][4];
#pragma unroll
    for (int mi = 0; mi < 4; mi++)
#pragma unroll
        for (int ni = 0; ni < 4; ni++) acc[mi][ni] = 0.f;

    const int fr = lane & 15;
    const int fq = (lane >> 4) * 8;

    for (int kk = 0; kk < Ka; kk += 32) {
        __syncthreads();
        GLDS(Ag0 + kk, Asp0);
        GLDS(Ag1 + kk, Asp1);
        GLDS(Bg0 + kk, Bsp0);
        GLDS(Bg1 + kk, Bsp1);
        __syncthreads();
        v8bf af[4], bv[4];
#pragma unroll
        for (int mi = 0; mi < 4; mi++)
            af[mi] = *(const v8bf*)&As[(wm * 64 + mi * 16 + fr) * 32 + fq];
#pragma unroll
        for (int ni = 0; ni < 4; ni++)
            bv[ni] = *(const v8bf*)&Bs[(wn * 64 + ni * 16 + fr) * 32 + fq];
#pragma unroll
        for (int mi = 0; mi < 4; mi++)
#pragma unroll
            for (int ni = 0; ni < 4; ni++)
                acc[mi][ni] = __builtin_amdgcn_mfma_f32_16x16x32_bf16(
                    af[mi], bv[ni], acc[mi][ni], 0, 0, 0);
    }

    // epilogue: D row = quad*4+reg, col = lane&15  [m89-verified]
    const int crow = wm * 64 + (lane >> 4) * 4;
    const int ccol = wn * 64 + (lane & 15);
    float bias_v[4];
#pragma unroll
    for (int ni = 0; ni < 4; ni++) bias_v[ni] = bias[col0 + ccol + ni * 16];

#pragma unroll
    for (int mi = 0; mi < 4; mi++) {
#pragma unroll
        for (int reg = 0; reg < 4; reg++) {
            int r = row0 + crow + mi * 16 + reg;
            if (r >= M) continue;
#pragma unroll
            for (int ni = 0; ni < 4; ni++) {
                int c = col0 + ccol + ni * 16;
                float v = acc[mi][ni][reg] + bias_v[ni];
                if (EPI == 1) v = fmaxf(v, 0.f);
                if (EPI == 2) v = 1.f / (1.f + expf(-v));
                if (OMODE & 1) Cb[(size_t)r * ldcb + c] = f2b(v);
                if (OMODE & 2) Cf[(size_t)r * 256 + c] = v;
            }
        }
    }
}

// ---------------------------------------------------------------------------
// Conversion / packing kernels
// ---------------------------------------------------------------------------
// zbx[KRR,288] bf16: [z_retr | o_retr | score | 0-pad]
__global__ void pack_zbx_k(const float* __restrict__ z, const float* __restrict__ o,
                           const float* __restrict__ s, u16* __restrict__ zbx)
{
    size_t g = (size_t)blockIdx.x * 256 + threadIdx.x;
    if (g >= (size_t)KRR * KAEXT) return;
    uint32_t r = (uint32_t)(g / KAEXT);
    uint32_t c = (uint32_t)(g - (size_t)r * KAEXT);
    float v;
    if (c < 256)      v = z[(size_t)r * 256 + c];
    else if (c < 264) v = o[(size_t)r * 8 + (c - 256)];
    else if (c == 264) v = s[r];
    else              v = 0.f;
    zbx[g] = f2b(v);
}

// Wt[o*Kpad + i] = (i<fi) ? W[i*ld + coloff + o] : 0   (fo=256 outputs)
__global__ void wtpose_k(const float* __restrict__ W, int ld, int coloff,
                         int fi, int Kpad, u16* __restrict__ Wt)
{
    int g = blockIdx.x * 256 + threadIdx.x;
    if (g >= 256 * Kpad) return;
    int o = g / Kpad, i = g - o * Kpad;
    Wt[g] = f2b(i < fi ? W[(size_t)i * ld + coloff + o] : 0.f);
}

__global__ void conv_f2b_k(const float* __restrict__ src, u16* __restrict__ dst, size_t n4)
{
    size_t g = (size_t)blockIdx.x * 256 + threadIdx.x;
    if (g >= n4) return;
    float4 v = ((const float4*)src)[g];
    ((ushort4*)dst)[g] = make_ushort4(f2b(v.x), f2b(v.y), f2b(v.z), f2b(v.w));
}

// gather h_cone[nids] -> acat cols 0..255 (bf16, ld 512)
__global__ void gather_hq_k(const float* __restrict__ hc, const int* __restrict__ nids,
                            u16* __restrict__ acat)
{
    int t = threadIdx.x;
    int k = blockIdx.x * 4 + (t >> 6);
    int c = t & 63;
    if (k >= KKP) return;
    int nid = nids[k];
    float4 v = ((const float4*)hc)[(size_t)nid * 64 + c];
    *(ushort4*)&acat[(size_t)k * 512 + c * 4] =
        make_ushort4(f2b(v.x), f2b(v.y), f2b(v.z), f2b(v.w));
}

// ---------------------------------------------------------------------------
// Attention
// ---------------------------------------------------------------------------
__launch_bounds__(256)
__global__ void att_scores_k(const u16* __restrict__ qh, const u16* __restrict__ kh,
                             float* __restrict__ att)
{
    int k = blockIdx.x;
    int t = threadIdx.x;
    int lane = t & 63;
    float qv = b2f(qh[(size_t)k * 256 + t]);
    const u16* khp = kh + (size_t)k * (RR * 256);
    float myscore = -1e30f;
    for (int r = 0; r < RR; r++) {
        float p = qv * b2f(khp[r * 256 + t]);
#pragma unroll
        for (int off = 1; off < 64; off <<= 1) p += __shfl_xor(p, off);
        if (lane == r) myscore = p * 0.125f;
    }
    float m = (lane < RR) ? myscore : -1e30f;
#pragma unroll
    for (int off = 1; off < 16; off <<= 1) m = fmaxf(m, __shfl_xor(m, off));
    float pe = (lane < RR) ? expf(myscore - m) : 0.f;
    float ssum = pe;
#pragma unroll
    for (int off = 1; off < 16; off <<= 1) ssum += __shfl_xor(ssum, off);
    if (lane < RR) att[(size_t)k * 64 + (t >> 6) * 16 + lane] = pe / ssum;
}

__launch_bounds__(256)
__global__ void att_apply_k(const float* __restrict__ att, const u16* __restrict__ vh,
                            u16* __restrict__ ctx)
{
    int k = blockIdx.x;
    int t = threadIdx.x;
    int h = t >> 6;
    __shared__ float a_s[64];
    if (t < 64) a_s[t] = att[(size_t)k * 64 + t];
    __syncthreads();
    const u16* vp = vh + (size_t)k * (RR * 256) + t;
    float acc = 0.f;
#pragma unroll
    for (int r = 0; r < RR; r++) acc = fmaf(a_s[h * 16 + r], b2f(vp[r * 256]), acc);
    ctx[(size_t)k * 256 + t] = f2b(acc);
}

// ---------------------------------------------------------------------------
// Scatter (last-write-wins)
// ---------------------------------------------------------------------------
__global__ void winner_k(const int* __restrict__ nids, int* __restrict__ winner)
{
    int gid = blockIdx.x * 256 + threadIdx.x;
    if (gid < KKP) atomicMax(&winner[nids[gid]], gid);
}

__global__ void scatter_h_k(const int* __restrict__ nids, const int* __restrict__ winner,
                            const float* __restrict__ hc, const float* __restrict__ gate,
                            const float* __restrict__ upd, u16* __restrict__ hb)
{
    int t = threadIdx.x;
    int k = blockIdx.x * 4 + (t >> 6);
    int c = t & 63;
    if (k >= KKP) return;
    int nid = nids[k];
    if (winner[nid] != k) return;
    float4 hv = ((const float4*)hc)[(size_t)nid * 64 + c];
    float4 gv = ((const float4*)gate)[(size_t)k * 64 + c];
    float4 uv = ((const float4*)upd)[(size_t)k * 64 + c];
    *(ushort4*)&hb[(size_t)nid * 256 + c * 4] = make_ushort4(
        f2b(hv.x + gv.x * uv.x), f2b(hv.y + gv.y * uv.y),
        f2b(hv.z + gv.z * uv.z), f2b(hv.w + gv.w * uv.w));
}

// ---------------------------------------------------------------------------
// CSR build
// ---------------------------------------------------------------------------
__global__ void edge_count_k(const int* __restrict__ dst, int* __restrict__ cnt, int e)
{
    int gid = blockIdx.x * 256 + threadIdx.x;
    if (gid < e) atomicAdd(&cnt[dst[gid]], 1);
}

__global__ void isd_k(const int* __restrict__ cnt, float* __restrict__ isd, int n)
{
    int gid = blockIdx.x * 256 + threadIdx.x;
    if (gid < n) isd[gid] = rsqrtf((float)(cnt[gid] + 1));
}

#define SCANB 1024
__global__ void scan1_k(const int* __restrict__ in, int* __restrict__ out,
                        int* __restrict__ bsums, int n)
{
    __shared__ int s[SCANB];
    int tid = threadIdx.x;
    int gid = blockIdx.x * SCANB + tid;
    int v = (gid < n) ? in[gid] : 0;
    s[tid] = v;
    __syncthreads();
    for (int off = 1; off < SCANB; off <<= 1) {
        int add = (tid >= off) ? s[tid - off] : 0;
        __syncthreads();
        s[tid] += add;
        __syncthreads();
    }
    if (gid < n) out[gid] = s[tid] - v;
    if (tid == SCANB - 1) bsums[blockIdx.x] = s[tid];
}

__global__ void scan2_k(int* bsums, int nb)
{
    if (threadIdx.x == 0 && blockIdx.x == 0) {
        int run = 0;
        for (int i = 0; i < nb; i++) { int v = bsums[i]; bsums[i] = run; run += v; }
    }
}

__global__ void scan3_k(int* __restrict__ out, const int* __restrict__ bsums, int n, int total)
{
    int gid = blockIdx.x * SCANB + threadIdx.x;
    if (gid < n) out[gid] += bsums[blockIdx.x];
    if (gid == 0) out[n] = total;
}

__global__ void csr_scatter_k(const int* __restrict__ src, const int* __restrict__ dst,
                              const int* __restrict__ row_start, int* __restrict__ cursor,
                              const float* __restrict__ isd,
                              int* __restrict__ csr_src, float* __restrict__ csr_w, int e)
{
    int gid = blockIdx.x * 256 + threadIdx.x;
    if (gid < e) {
        int sP = src[gid], dP = dst[gid];
        int pos = row_start[dP] + atomicAdd(&cursor[dP], 1);
        csr_src[pos] = sP;
        csr_w[pos] = isd[sP] * isd[dP];
    }
}

// GCN aggregation (bf16 features, fp32 accumulate)
template <int RELU>
__launch_bounds__(256)
__global__ void gnn_agg_k(const u16* __restrict__ x, const int* __restrict__ row_start,
                          const int* __restrict__ csr_src, const float* __restrict__ csr_w,
                          const float* __restrict__ isd, u16* __restrict__ out)
{
    int i = blockIdx.x;
    int c = threadIdx.x;
    float si = isd[i];
    float acc = b2f(x[(size_t)i * 256 + c]) * si * si;
    int s0 = row_start[i], s1 = row_start[i + 1];
    for (int j = s0; j < s1; j++) {
        int sP = csr_src[j];
        float wv = csr_w[j];
        acc = fmaf(b2f(x[(size_t)sP * 256 + c]), wv, acc);
    }
    if (RELU) acc = fmaxf(acc, 0.f);
    out[(size_t)i * 256 + c] = f2b(acc);
}

// head layer-2 + teacher add
__launch_bounds__(256)
__global__ void head_out_k(const u16* __restrict__ thid, const float* __restrict__ W2,
                           const float* __restrict__ b2, const float* __restrict__ teacher,
                           float* __restrict__ outp, int n)
{
    __shared__ float ts[32][257];
    __shared__ float w2s[256 * 8];
    int t = threadIdx.x;
    int rbase = blockIdx.x * 32;
    for (int i = t; i < 2048; i += 256) w2s[i] = W2[i];
    for (int i = t; i < 32 * 256; i += 256) {
        int rr = i >> 8, cc = i & 255;
        int gr = rbase + rr;
        ts[rr][cc] = (gr < n) ? b2f(thid[(size_t)gr * 256 + cc]) : 0.f;
    }
    __syncthreads();
    int rr = t >> 3, cc = t & 7;
    int gr = rbase + rr;
    if (gr >= n) return;
    float acc = b2[cc];
    for (int kk = 0; kk < 256; kk++)
        acc = fmaf(ts[rr][kk], w2s[kk * 8 + cc], acc);
    outp[(size_t)gr * 8 + cc] = teacher[(size_t)gr * 8 + cc] + acc;
}

// ---------------------------------------------------------------------------
// Host launcher
// ---------------------------------------------------------------------------
extern "C" void kernel_launch(void* const* d_in, const int* in_sizes, int n_in,
                              void* d_out, int out_size, void* d_ws, size_t ws_size,
                              hipStream_t stream)
{
    (void)in_sizes; (void)n_in; (void)out_size; (void)ws_size;
    const float* h_cone     = (const float*)d_in[0];
    const float* z_retr     = (const float*)d_in[1];
    const float* o_retr     = (const float*)d_in[2];
    const float* retr_score = (const float*)d_in[3];
    const float* teacher    = (const float*)d_in[4];
    const int*   nids       = (const int*)d_in[5];
    const int*   edge       = (const int*)d_in[6];
    const float* rp_W1 = (const float*)d_in[7];   const float* rp_b1 = (const float*)d_in[8];
    const float* rp_W2 = (const float*)d_in[9];   const float* rp_b2 = (const float*)d_in[10];
    const float* qp_W  = (const float*)d_in[11];  const float* qp_b  = (const float*)d_in[12];
    const float* inW   = (const float*)d_in[13];  const float* inB   = (const float*)d_in[14];
    const float* outW  = (const float*)d_in[15];  const float* outB  = (const float*)d_in[16];
    const float* gW1   = (const float*)d_in[17];  const float* gB1   = (const float*)d_in[18];
    const float* gW2   = (const float*)d_in[19];  const float* gB2   = (const float*)d_in[20];
    const float* uW1   = (const float*)d_in[21];  const float* uB1   = (const float*)d_in[22];
    const float* uW2   = (const float*)d_in[23];  const float* uB2   = (const float*)d_in[24];
    const float* gnW1  = (const float*)d_in[25];  const float* gnB1  = (const float*)d_in[26];
    const float* gnW2  = (const float*)d_in[27];  const float* gnB2  = (const float*)d_in[28];
    const float* hW1   = (const float*)d_in[29];  const float* hB1   = (const float*)d_in[30];
    const float* hW2   = (const float*)d_in[31];  const float* hB2   = (const float*)d_in[32];
    float* out = (float*)d_out;

    char* ws = (char*)d_ws;
    size_t off = 0;
    auto alloc = [&](size_t bytes) -> void* {
        void* p = ws + off;
        off = (off + bytes + 255) & ~(size_t)255;
        return p;
    };
    u16* zbx    = (u16*)alloc((size_t)KRR * KAEXT * 2);   // 184.3 MB; GNN region later
    u16* hidden = (u16*)alloc((size_t)KRR * 256 * 2);     // hidden -> vh
    u16* kv     = (u16*)alloc((size_t)KRR * 256 * 2);
    u16* khb    = (u16*)alloc((size_t)KRR * 256 * 2);
    u16* qtmp   = (u16*)alloc((size_t)KP * 256 * 2);
    u16* qhb    = (u16*)alloc((size_t)KP * 256 * 2);
    float* att  = (float*)alloc((size_t)KKP * 64 * 4);
    u16* ctxb   = (u16*)alloc((size_t)KP * 256 * 2);
    u16* acat   = (u16*)alloc((size_t)KP * 512 * 2);
    u16* ghid   = (u16*)alloc((size_t)KP * 256 * 2);
    float* gate = (float*)alloc((size_t)KP * 256 * 4);
    u16* uhid   = (u16*)alloc((size_t)KP * 256 * 2);
    float* upd  = (float*)alloc((size_t)KP * 256 * 4);
    // 13 transposed weights
    u16* wt_rp1 = (u16*)alloc(256 * KAEXT * 2);
    u16* wt_rp2 = (u16*)alloc(256 * 256 * 2);
    u16* wt_qp  = (u16*)alloc(256 * 256 * 2);
    u16* wt_q   = (u16*)alloc(256 * 256 * 2);
    u16* wt_kk  = (u16*)alloc(256 * 256 * 2);
    u16* wt_v   = (u16*)alloc(256 * 256 * 2);
    u16* wt_o   = (u16*)alloc(256 * 256 * 2);
    u16* wt_g1  = (u16*)alloc(256 * 512 * 2);
    u16* wt_g2  = (u16*)alloc(256 * 256 * 2);
    u16* wt_u1  = (u16*)alloc(256 * 256 * 2);
    u16* wt_u2  = (u16*)alloc(256 * 256 * 2);
    u16* wt_gn1 = (u16*)alloc(256 * 256 * 2);
    u16* wt_gn2 = (u16*)alloc(256 * 256 * 2);
    u16* wt_h1  = (u16*)alloc(256 * 256 * 2);
    int*   winner    = (int*)alloc(NN * 4);
    int*   cnt       = (int*)alloc(NN * 4);
    int*   cursor    = (int*)alloc(NN * 4);
    int*   row_start = (int*)alloc((NN + 1) * 4);
    int*   bsums     = (int*)alloc(1024 * 4);
    float* isd       = (float*)alloc(NN * 4);
    int*   csr_src   = (int*)alloc((size_t)EE * 4);
    float* csr_w     = (float*)alloc((size_t)EE * 4);

    // GNN stage overlays the zbx region (dead after rp1 GEMM): 3 buffers of NP rows
    const size_t NPE = (size_t)NP * 256;     // elements
    u16* gZ0 = zbx;                          // hb -> x2 -> thid
    u16* gZ1 = zbx + NPE;                    // x1 -> h2
    u16* gZ2 = zbx + 2 * NPE;                // h1

    const int* esrc = edge;
    const int* edst = edge + EE;

    auto gemmB = [&](int epi, const u16* A, int lda, int M, int Ka, const u16* Wt,
                     const float* bias, u16* Cb, int ldcb, float* Cf) {
        dim3 grid((M + 127) / 128, 2);
        if (Cf) {
            if (epi == 2) gemm_bf_k<2, 2><<<grid, 256, 0, stream>>>(A, lda, M, Ka, Wt, bias, Cb, ldcb, Cf);
            else          gemm_bf_k<0, 2><<<grid, 256, 0, stream>>>(A, lda, M, Ka, Wt, bias, Cb, ldcb, Cf);
        } else {
            if (epi == 1) gemm_bf_k<1, 1><<<grid, 256, 0, stream>>>(A, lda, M, Ka, Wt, bias, Cb, ldcb, Cf);
            else          gemm_bf_k<0, 1><<<grid, 256, 0, stream>>>(A, lda, M, Ka, Wt, bias, Cb, ldcb, Cf);
        }
    };
    auto wtp = [&](const float* W, int ld, int coloff, int fi, int Kpad, u16* Wt) {
        wtpose_k<<<(256 * Kpad + 255) / 256, 256, 0, stream>>>(W, ld, coloff, fi, Kpad, Wt);
    };

    // ---- CSR prep ----
    hipMemsetAsync(cnt, 0, NN * 4, stream);
    hipMemsetAsync(cursor, 0, NN * 4, stream);
    edge_count_k<<<(EE + 255) / 256, 256, 0, stream>>>(edst, cnt, EE);
    isd_k<<<(NN + 255) / 256, 256, 0, stream>>>(cnt, isd, NN);
    int nb = (NN + SCANB - 1) / SCANB;
    scan1_k<<<nb, SCANB, 0, stream>>>(cnt, row_start, bsums, NN);
    scan2_k<<<1, 64, 0, stream>>>(bsums, nb);
    scan3_k<<<nb, SCANB, 0, stream>>>(row_start, bsums, NN, EE);
    csr_scatter_k<<<(EE + 255) / 256, 256, 0, stream>>>(esrc, edst, row_start, cursor, isd,
                                                        csr_src, csr_w, EE);

    // ---- weight transposes + input packing ----
    wtp(rp_W1, 256, 0, 265, KAEXT, wt_rp1);
    wtp(rp_W2, 256, 0, 256, 256, wt_rp2);
    wtp(qp_W,  256, 0, 256, 256, wt_qp);
    wtp(inW,   768, 0,   256, 256, wt_q);
    wtp(inW,   768, 256, 256, 256, wt_kk);
    wtp(inW,   768, 512, 256, 256, wt_v);
    wtp(outW,  256, 0, 256, 256, wt_o);
    wtp(gW1,   256, 0, 512, 512, wt_g1);
    wtp(gW2,   256, 0, 256, 256, wt_g2);
    wtp(uW1,   256, 0, 256, 256, wt_u1);
    wtp(uW2,   256, 0, 256, 256, wt_u2);
    wtp(gnW1,  256, 0, 256, 256, wt_gn1);
    wtp(gnW2,  256, 0, 256, 256, wt_gn2);
    wtp(hW1,   256, 0, 256, 256, wt_h1);
    {
        size_t tot = (size_t)KRR * KAEXT;
        pack_zbx_k<<<(int)((tot + 255) / 256), 256, 0, stream>>>(z_retr, o_retr, retr_score, zbx);
    }
    gather_hq_k<<<(KKP + 3) / 4, 256, 0, stream>>>(h_cone, nids, acat);

    // ---- retrieval MLP + K/V projections ----
    gemmB(1, zbx, KAEXT, KRR, KAEXT, wt_rp1, rp_b1, hidden, 256, nullptr);
    gemmB(0, hidden, 256, KRR, 256, wt_rp2, rp_b2, kv, 256, nullptr);
    gemmB(0, kv, 256, KRR, 256, wt_kk, inB + 256, khb, 256, nullptr);

    // ---- queries ----
    gemmB(0, acat, 512, KKP, 256, wt_qp, qp_b, qtmp, 256, nullptr);
    gemmB(0, qtmp, 256, KKP, 256, wt_q, inB, qhb, 256, nullptr);

    // ---- attention ----
    att_scores_k<<<KKP, 256, 0, stream>>>(qhb, khb, att);
    gemmB(0, kv, 256, KRR, 256, wt_v, inB + 512, hidden, 256, nullptr);   // vh -> hidden
    att_apply_k<<<KKP, 256, 0, stream>>>(att, hidden, ctxb);
    gemmB(0, ctxb, 256, KKP, 256, wt_o, outB, acat + 256, 512, nullptr);  // rctx -> acat[,256:]

    // ---- gate / update ----
    gemmB(1, acat, 512, KKP, 512, wt_g1, gB1, ghid, 256, nullptr);
    gemmB(2, ghid, 256, KKP, 256, wt_g2, gB2, nullptr, 0, gate);
    gemmB(1, acat + 256, 512, KKP, 256, wt_u1, uB1, uhid, 256, nullptr);
    gemmB(0, uhid, 256, KKP, 256, wt_u2, uB2, nullptr, 0, upd);

    // ---- scatter into hb (bf16 copy of h_cone, winner rows overwritten) ----
    conv_f2b_k<<<(int)(((size_t)NN * 64 + 255) / 256), 256, 0, stream>>>(h_cone, gZ0, (size_t)NN * 64);
    hipMemsetAsync(winner, 0xFF, NN * 4, stream);
    winner_k<<<(KKP + 255) / 256, 256, 0, stream>>>(nids, winner);
    scatter_h_k<<<(KKP + 3) / 4, 256, 0, stream>>>(nids, winner, h_cone, gate, upd, gZ0);

    // ---- cone GNN ----
    gemmB(0, gZ0, 256, NN, 256, wt_gn1, gnB1, gZ1, 256, nullptr);                 // x1
    gnn_agg_k<1><<<NN, 256, 0, stream>>>(gZ1, row_start, csr_src, csr_w, isd, gZ2); // h1
    gemmB(0, gZ2, 256, NN, 256, wt_gn2, gnB2, gZ0, 256, nullptr);                 // x2
    gnn_agg_k<0><<<NN, 256, 0, stream>>>(gZ0, row_start, csr_src, csr_w, isd, gZ1); // h2
    gemmB(1, gZ1, 256, NN, 256, wt_h1, hB1, gZ0, 256, nullptr);                   // thid
    head_out_k<<<(NN + 31) / 32, 256, 0, stream>>>(gZ0, hW2, hB2, teacher, out, NN);
}

// Round 3
// 1792.221 us; speedup vs baseline: 2.4193x; 1.1408x over previous
//
#include <hip/hip_runtime.h>
#include <cstdint>
#include <cstddef>

typedef unsigned short u16;

// Problem constants
#define NN    100000
#define OUTD  8
#define KKP   20000
#define RR    16
#define EE    800000
#define KRR   (KKP*RR)   // 320000
#define KP    20096      // 157*128
#define NP    100096     // 782*128

typedef __bf16 v8bf __attribute__((ext_vector_type(8)));
typedef float  v4f  __attribute__((ext_vector_type(4)));

__device__ __forceinline__ float b2f(u16 u) {
    union { uint32_t i; float f; } v; v.i = (uint32_t)u << 16; return v.f;
}
__device__ __forceinline__ u16 f2b(float f) {
    union { float f; uint32_t i; } v; v.f = f;
    uint32_t i = v.i;
    return (u16)((i + 0x7fffu + ((i >> 16) & 1u)) >> 16);
}
__device__ __forceinline__ uint32_t pk2(float a, float b) {
    return (uint32_t)f2b(a) | ((uint32_t)f2b(b) << 16);
}

#define GLDS(g, l) __builtin_amdgcn_global_load_lds(                         \
    (const __attribute__((address_space(1))) void*)(g),                      \
    (__attribute__((address_space(3))) void*)(l), 16, 0, 0)

// ---------------------------------------------------------------------------
// bf16 MFMA GEMM: C[M,Nout] = act(A[M,Ka] @ Wt[Nout,Ka]^T + bias)
// 128x128 tile, BK=32, 4 waves, 4x4 16x16x32 frags per wave.
// EPI: 0 none, 1 relu, 2 sigmoid.  OMODE: 1 bf16 out, 2 f32 out.
// A32: A is fp32, register-stage + convert into LDS (GLDS for B only).
// RETR: add o_retr/score extra K-rows of rp_W1 in epilogue (pre-activation).
// ---------------------------------------------------------------------------
template <int EPI, int OMODE, int A32, int RETR>
__launch_bounds__(256)
__global__ void gemm_bf_k(const void* __restrict__ Av, int lda, int M, int Ka,
                          const u16* __restrict__ Wt,
                          const float* __restrict__ bias,
                          void* __restrict__ Cv, int ldc,
                          const float* __restrict__ o_ex,
                          const float* __restrict__ s_ex,
                          const float* __restrict__ Wex)
{
    __shared__ u16 As[128 * 32];
    __shared__ u16 Bs[128 * 32];
    const int row0 = blockIdx.x * 128;
    const int col0 = blockIdx.y * 128;
    const int t    = threadIdx.x;
    const int lane = t & 63;
    const int w    = t >> 6;
    const int wm   = w & 1, wn = w >> 1;

    const int idx0 = t, idx1 = t + 256;
    const u16* Ab = (const u16*)Av;
    const float* Af = (const float*)Av;
    const u16* Ag0 = Ab + (size_t)(row0 + (idx0 >> 2)) * lda + (idx0 & 3) * 8;
    const u16* Ag1 = Ab + (size_t)(row0 + (idx1 >> 2)) * lda + (idx1 & 3) * 8;
    const float* Af0 = Af + (size_t)(row0 + (idx0 >> 2)) * lda + (idx0 & 3) * 8;
    const float* Af1 = Af + (size_t)(row0 + (idx1 >> 2)) * lda + (idx1 & 3) * 8;
    const u16* Bg0 = Wt + (size_t)(col0 + (idx0 >> 2)) * Ka + (idx0 & 3) * 8;
    const u16* Bg1 = Wt + (size_t)(col0 + (idx1 >> 2)) * Ka + (idx1 & 3) * 8;
    u16* Asp0 = &As[idx0 * 8];
    u16* Asp1 = &As[idx1 * 8];
    u16* Bsp0 = &Bs[idx0 * 8];
    u16* Bsp1 = &Bs[idx1 * 8];

    v4f acc[4][4];
#pragma unroll
    for (int mi = 0; mi < 4; mi++)
#pragma unroll
        for (int ni = 0; ni < 4; ni++) acc[mi][ni] = 0.f;

    const int fr = lane & 15;
    const int fq = (lane >> 4) * 8;

    for (int kk = 0; kk < Ka; kk += 32) {
        float4 a00, a01, a10, a11;
        if (A32) {
            a00 = *(const float4*)(Af0 + kk);
            a01 = *(const float4*)(Af0 + kk + 4);
            a10 = *(const float4*)(Af1 + kk);
            a11 = *(const float4*)(Af1 + kk + 4);
        }
        __syncthreads();
        if (A32) {
            uint4 u0, u1;
            u0.x = pk2(a00.x, a00.y); u0.y = pk2(a00.z, a00.w);
            u0.z = pk2(a01.x, a01.y); u0.w = pk2(a01.z, a01.w);
            u1.x = pk2(a10.x, a10.y); u1.y = pk2(a10.z, a10.w);
            u1.z = pk2(a11.x, a11.y); u1.w = pk2(a11.z, a11.w);
            *(uint4*)Asp0 = u0;
            *(uint4*)Asp1 = u1;
        } else {
            GLDS(Ag0 + kk, Asp0);
            GLDS(Ag1 + kk, Asp1);
        }
        GLDS(Bg0 + kk, Bsp0);
        GLDS(Bg1 + kk, Bsp1);
        __syncthreads();
        v8bf af[4], bv[4];
#pragma unroll
        for (int mi = 0; mi < 4; mi++)
            af[mi] = *(const v8bf*)&As[(wm * 64 + mi * 16 + fr) * 32 + fq];
#pragma unroll
        for (int ni = 0; ni < 4; ni++)
            bv[ni] = *(const v8bf*)&Bs[(wn * 64 + ni * 16 + fr) * 32 + fq];
#pragma unroll
        for (int mi = 0; mi < 4; mi++)
#pragma unroll
            for (int ni = 0; ni < 4; ni++)
                acc[mi][ni] = __builtin_amdgcn_mfma_f32_16x16x32_bf16(
                    af[mi], bv[ni], acc[mi][ni], 0, 0, 0);
    }

    // D row = quad*4+reg, col = lane&15  [m89-verified]
    const int crow = wm * 64 + (lane >> 4) * 4;
    const int ccol = wn * 64 + (lane & 15);
    float bias_v[4];
#pragma unroll
    for (int ni = 0; ni < 4; ni++) bias_v[ni] = bias[col0 + ccol + ni * 16];

    u16*   Cb = (u16*)Cv;
    float* Cf = (float*)Cv;
#pragma unroll
    for (int mi = 0; mi < 4; mi++) {
#pragma unroll
        for (int reg = 0; reg < 4; reg++) {
            int r = row0 + crow + mi * 16 + reg;
            if (r >= M) continue;
            float ov[8], sv;
            if (RETR) {
#pragma unroll
                for (int u = 0; u < 8; u++) ov[u] = o_ex[(size_t)r * 8 + u];
                sv = s_ex[r];
            }
#pragma unroll
            for (int ni = 0; ni < 4; ni++) {
                int c = col0 + ccol + ni * 16;
                float v = acc[mi][ni][reg] + bias_v[ni];
                if (RETR) {
                    float e = sv * Wex[8 * 256 + c];
#pragma unroll
                    for (int u = 0; u < 8; u++) e = fmaf(ov[u], Wex[u * 256 + c], e);
                    v += e;
                }
                if (EPI == 1) v = fmaxf(v, 0.f);
                if (EPI == 2) v = 1.f / (1.f + expf(-v));
                if (OMODE == 1) Cb[(size_t)r * ldc + c] = f2b(v);
                else            Cf[(size_t)r * ldc + c] = v;
            }
        }
    }
}

// ---------------------------------------------------------------------------
// Weight prep
// ---------------------------------------------------------------------------
// Wt[o*Kpad + i] = (i<fi) ? W[i*ld + coloff + o] : 0   (256 outputs)
__global__ void wtpose_k(const float* __restrict__ W, int ld, int coloff,
                         int fi, int Kpad, u16* __restrict__ Wt)
{
    int g = blockIdx.x * 256 + threadIdx.x;
    if (g >= 256 * Kpad) return;
    int o = g / Kpad, i = g - o * Kpad;
    Wt[g] = f2b(i < fi ? W[(size_t)i * ld + coloff + o] : 0.f);
}

// Fused weight: Wt_out[j*256+i] = sum_m A[i,m] * Binw[m*ldb + off + j]
// Block 0 also writes bias_out[j] = bb[j] + sum_m ba[m]*Binw[m,j]
__global__ void wfuse_k(const float* __restrict__ A, const float* __restrict__ Binw,
                        int ldb, int off, const float* __restrict__ ba,
                        const float* __restrict__ bb,
                        u16* __restrict__ Wt_out, float* __restrict__ bias_out)
{
    __shared__ float As[256];
    __shared__ float bs[256];
    int i = blockIdx.x, j = threadIdx.x;
    As[j] = A[(size_t)i * 256 + j];
    bs[j] = ba[j];
    __syncthreads();
    float acc = 0.f, accb = 0.f;
    for (int m = 0; m < 256; m++) {
        float bv = Binw[(size_t)m * ldb + off + j];
        acc = fmaf(As[m], bv, acc);
        if (i == 0) accb = fmaf(bs[m], bv, accb);
    }
    Wt_out[(size_t)j * 256 + i] = f2b(acc);
    if (i == 0) bias_out[j] = bb[j] + accb;
}

__global__ void conv_f2b_k(const float* __restrict__ src, u16* __restrict__ dst, size_t n4)
{
    size_t g = (size_t)blockIdx.x * 256 + threadIdx.x;
    if (g >= n4) return;
    float4 v = ((const float4*)src)[g];
    ((ushort4*)dst)[g] = make_ushort4(f2b(v.x), f2b(v.y), f2b(v.z), f2b(v.w));
}

// gather h_cone[nids] -> acat cols 0..255 (bf16, ld 512)
__global__ void gather_hq_k(const float* __restrict__ hc, const int* __restrict__ nids,
                            u16* __restrict__ acat)
{
    int t = threadIdx.x;
    int k = blockIdx.x * 4 + (t >> 6);
    int c = t & 63;
    if (k >= KKP) return;
    int nid = nids[k];
    float4 v = ((const float4*)hc)[(size_t)nid * 64 + c];
    *(ushort4*)&acat[(size_t)k * 512 + c * 4] =
        make_ushort4(f2b(v.x), f2b(v.y), f2b(v.z), f2b(v.w));
}

// ---------------------------------------------------------------------------
// Fused attention: scores + softmax + apply.  khv [KRR,512]: k|v halves.
// Wave w handles head w (dims w*64..w*64+63 = thread t's column t).
// ---------------------------------------------------------------------------
__launch_bounds__(256)
__global__ void att_fused_k(const u16* __restrict__ qh, const u16* __restrict__ khv,
                            u16* __restrict__ ctx)
{
    int k = blockIdx.x;
    int t = threadIdx.x;
    int lane = t & 63;
    float qv = b2f(qh[(size_t)k * 256 + t]);
    const u16* kp = khv + (size_t)k * (RR * 512) + t;
    const u16* vp = kp + 256;
    float myscore = -1e30f;
#pragma unroll
    for (int r = 0; r < RR; r++) {
        float p = qv * b2f(kp[r * 512]);
#pragma unroll
        for (int off = 1; off < 64; off <<= 1) p += __shfl_xor(p, off);
        if (lane == r) myscore = p * 0.125f;   // 1/sqrt(64)
    }
    float m = (lane < RR) ? myscore : -1e30f;
#pragma unroll
    for (int off = 1; off < 16; off <<= 1) m = fmaxf(m, __shfl_xor(m, off));
    float pe = (lane < RR) ? expf(myscore - m) : 0.f;
    float ssum = pe;
#pragma unroll
    for (int off = 1; off < 16; off <<= 1) ssum += __shfl_xor(ssum, off);
    float pn = pe / ssum;                      // valid on lanes 0..15
    float acc = 0.f;
#pragma unroll
    for (int r = 0; r < RR; r++) {
        float ar = __shfl(pn, r);
        acc = fmaf(ar, b2f(vp[r * 512]), acc);
    }
    ctx[(size_t)k * 256 + t] = f2b(acc);
}

// ---------------------------------------------------------------------------
// Scatter (last-write-wins)
// ---------------------------------------------------------------------------
__global__ void winner_k(const int* __restrict__ nids, int* __restrict__ winner)
{
    int gid = blockIdx.x * 256 + threadIdx.x;
    if (gid < KKP) atomicMax(&winner[nids[gid]], gid);
}

__global__ void scatter_h_k(const int* __restrict__ nids, const int* __restrict__ winner,
                            const float* __restrict__ hc, const float* __restrict__ gate,
                            const float* __restrict__ upd, u16* __restrict__ hb)
{
    int t = threadIdx.x;
    int k = blockIdx.x * 4 + (t >> 6);
    int c = t & 63;
    if (k >= KKP) return;
    int nid = nids[k];
    if (winner[nid] != k) return;
    float4 hv = ((const float4*)hc)[(size_t)nid * 64 + c];
    float4 gv = ((const float4*)gate)[(size_t)k * 64 + c];
    float4 uv = ((const float4*)upd)[(size_t)k * 64 + c];
    *(ushort4*)&hb[(size_t)nid * 256 + c * 4] = make_ushort4(
        f2b(hv.x + gv.x * uv.x), f2b(hv.y + gv.y * uv.y),
        f2b(hv.z + gv.z * uv.z), f2b(hv.w + gv.w * uv.w));
}

// ---------------------------------------------------------------------------
// CSR build
// ---------------------------------------------------------------------------
__global__ void edge_count_k(const int* __restrict__ dst, int* __restrict__ cnt, int e)
{
    int gid = blockIdx.x * 256 + threadIdx.x;
    if (gid < e) atomicAdd(&cnt[dst[gid]], 1);
}

__global__ void isd_k(const int* __restrict__ cnt, float* __restrict__ isd, int n)
{
    int gid = blockIdx.x * 256 + threadIdx.x;
    if (gid < n) isd[gid] = rsqrtf((float)(cnt[gid] + 1));
}

#define SCANB 1024
__global__ void scan1_k(const int* __restrict__ in, int* __restrict__ out,
                        int* __restrict__ bsums, int n)
{
    __shared__ int s[SCANB];
    int tid = threadIdx.x;
    int gid = blockIdx.x * SCANB + tid;
    int v = (gid < n) ? in[gid] : 0;
    s[tid] = v;
    __syncthreads();
    for (int off = 1; off < SCANB; off <<= 1) {
        int add = (tid >= off) ? s[tid - off] : 0;
        __syncthreads();
        s[tid] += add;
        __syncthreads();
    }
    if (gid < n) out[gid] = s[tid] - v;
    if (tid == SCANB - 1) bsums[blockIdx.x] = s[tid];
}

__global__ void scan2_k(int* bsums, int nb)
{
    if (threadIdx.x == 0 && blockIdx.x == 0) {
        int run = 0;
        for (int i = 0; i < nb; i++) { int v = bsums[i]; bsums[i] = run; run += v; }
    }
}

__global__ void scan3_k(int* __restrict__ out, const int* __restrict__ bsums, int n, int total)
{
    int gid = blockIdx.x * SCANB + threadIdx.x;
    if (gid < n) out[gid] += bsums[blockIdx.x];
    if (gid == 0) out[n] = total;
}

__global__ void csr_scatter_k(const int* __restrict__ src, const int* __restrict__ dst,
                              const int* __restrict__ row_start, int* __restrict__ cursor,
                              const float* __restrict__ isd,
                              int* __restrict__ csr_src, float* __restrict__ csr_w, int e)
{
    int gid = blockIdx.x * 256 + threadIdx.x;
    if (gid < e) {
        int sP = src[gid], dP = dst[gid];
        int pos = row_start[dP] + atomicAdd(&cursor[dP], 1);
        csr_src[pos] = sP;
        csr_w[pos] = isd[sP] * isd[dP];
    }
}

// GCN aggregation: wave per node, ushort4 per lane (512B per row read)
template <int RELU>
__launch_bounds__(256)
__global__ void gnn_agg_k(const u16* __restrict__ x, const int* __restrict__ row_start,
                          const int* __restrict__ csr_src, const float* __restrict__ csr_w,
                          const float* __restrict__ isd, u16* __restrict__ outp)
{
    int node = blockIdx.x * 4 + (threadIdx.x >> 6);
    int lane = threadIdx.x & 63;
    if (node >= NN) return;
    float si = isd[node];
    float sii = si * si;
    ushort4 sv = ((const ushort4*)x)[(size_t)node * 64 + lane];
    float a0 = b2f(sv.x) * sii, a1 = b2f(sv.y) * sii;
    float a2 = b2f(sv.z) * sii, a3 = b2f(sv.w) * sii;
    int s0 = row_start[node], s1 = row_start[node + 1];
    for (int j = s0; j < s1; j++) {
        int sP = csr_src[j];
        float wv = csr_w[j];
        ushort4 v = ((const ushort4*)x)[(size_t)sP * 64 + lane];
        a0 = fmaf(b2f(v.x), wv, a0);
        a1 = fmaf(b2f(v.y), wv, a1);
        a2 = fmaf(b2f(v.z), wv, a2);
        a3 = fmaf(b2f(v.w), wv, a3);
    }
    if (RELU) {
        a0 = fmaxf(a0, 0.f); a1 = fmaxf(a1, 0.f);
        a2 = fmaxf(a2, 0.f); a3 = fmaxf(a3, 0.f);
    }
    ((ushort4*)outp)[(size_t)node * 64 + lane] =
        make_ushort4(f2b(a0), f2b(a1), f2b(a2), f2b(a3));
}

// head layer-2 + teacher add
__launch_bounds__(256)
__global__ void head_out_k(const u16* __restrict__ thid, const float* __restrict__ W2,
                           const float* __restrict__ b2, const float* __restrict__ teacher,
                           float* __restrict__ outp, int n)
{
    __shared__ float ts[32][257];
    __shared__ float w2s[256 * 8];
    int t = threadIdx.x;
    int rbase = blockIdx.x * 32;
    for (int i = t; i < 2048; i += 256) w2s[i] = W2[i];
    for (int i = t; i < 32 * 256; i += 256) {
        int rr = i >> 8, cc = i & 255;
        int gr = rbase + rr;
        ts[rr][cc] = (gr < n) ? b2f(thid[(size_t)gr * 256 + cc]) : 0.f;
    }
    __syncthreads();
    int rr = t >> 3, cc = t & 7;
    int gr = rbase + rr;
    if (gr >= n) return;
    float acc = b2[cc];
    for (int kk = 0; kk < 256; kk++)
        acc = fmaf(ts[rr][kk], w2s[kk * 8 + cc], acc);
    outp[(size_t)gr * 8 + cc] = teacher[(size_t)gr * 8 + cc] + acc;
}

// ---------------------------------------------------------------------------
// Host launcher
// ---------------------------------------------------------------------------
extern "C" void kernel_launch(void* const* d_in, const int* in_sizes, int n_in,
                              void* d_out, int out_size, void* d_ws, size_t ws_size,
                              hipStream_t stream)
{
    (void)in_sizes; (void)n_in; (void)out_size; (void)ws_size;
    const float* h_cone     = (const float*)d_in[0];
    const float* z_retr     = (const float*)d_in[1];
    const float* o_retr     = (const float*)d_in[2];
    const float* retr_score = (const float*)d_in[3];
    const float* teacher    = (const float*)d_in[4];
    const int*   nids       = (const int*)d_in[5];
    const int*   edge       = (const int*)d_in[6];
    const float* rp_W1 = (const float*)d_in[7];   const float* rp_b1 = (const float*)d_in[8];
    const float* rp_W2 = (const float*)d_in[9];   const float* rp_b2 = (const float*)d_in[10];
    const float* qp_W  = (const float*)d_in[11];  const float* qp_b  = (const float*)d_in[12];
    const float* inW   = (const float*)d_in[13];  const float* inB   = (const float*)d_in[14];
    const float* outW  = (const float*)d_in[15];  const float* outB  = (const float*)d_in[16];
    const float* gW1   = (const float*)d_in[17];  const float* gB1   = (const float*)d_in[18];
    const float* gW2   = (const float*)d_in[19];  const float* gB2   = (const float*)d_in[20];
    const float* uW1   = (const float*)d_in[21];  const float* uB1   = (const float*)d_in[22];
    const float* uW2   = (const float*)d_in[23];  const float* uB2   = (const float*)d_in[24];
    const float* gnW1  = (const float*)d_in[25];  const float* gnB1  = (const float*)d_in[26];
    const float* gnW2  = (const float*)d_in[27];  const float* gnB2  = (const float*)d_in[28];
    const float* hW1   = (const float*)d_in[29];  const float* hB1   = (const float*)d_in[30];
    const float* hW2   = (const float*)d_in[31];  const float* hB2   = (const float*)d_in[32];
    float* out = (float*)d_out;

    char* ws = (char*)d_ws;
    size_t off = 0;
    auto alloc = [&](size_t bytes) -> void* {
        void* p = ws + off;
        off = (off + bytes + 255) & ~(size_t)255;
        return p;
    };
    u16* hidden = (u16*)alloc((size_t)KRR * 256 * 2);   // rp1 out; GNN overlays later
    u16* khv    = (u16*)alloc((size_t)KRR * 512 * 2);   // [k|v]
    u16* qhb    = (u16*)alloc((size_t)KP * 256 * 2);
    u16* ctxb   = (u16*)alloc((size_t)KP * 256 * 2);
    u16* acat   = (u16*)alloc((size_t)KP * 512 * 2);
    u16* ghid   = (u16*)alloc((size_t)KP * 256 * 2);
    float* gate = (float*)alloc((size_t)KP * 256 * 4);
    u16* uhid   = (u16*)alloc((size_t)KP * 256 * 2);
    float* upd  = (float*)alloc((size_t)KP * 256 * 4);
    u16* wt_rp1 = (u16*)alloc(256 * 256 * 2);
    u16* wt_kv  = (u16*)alloc(512 * 256 * 2);
    u16* wt_qf  = (u16*)alloc(256 * 256 * 2);
    u16* wt_o   = (u16*)alloc(256 * 256 * 2);
    u16* wt_g1  = (u16*)alloc(256 * 512 * 2);
    u16* wt_g2  = (u16*)alloc(256 * 256 * 2);
    u16* wt_u1  = (u16*)alloc(256 * 256 * 2);
    u16* wt_u2  = (u16*)alloc(256 * 256 * 2);
    u16* wt_gn1 = (u16*)alloc(256 * 256 * 2);
    u16* wt_gn2 = (u16*)alloc(256 * 256 * 2);
    u16* wt_h1  = (u16*)alloc(256 * 256 * 2);
    float* bias_kv = (float*)alloc(512 * 4);
    float* bias_qf = (float*)alloc(256 * 4);
    int*   winner    = (int*)alloc(NN * 4);
    int*   cnt       = (int*)alloc(NN * 4);
    int*   cursor    = (int*)alloc(NN * 4);
    int*   row_start = (int*)alloc((NN + 1) * 4);
    int*   bsums     = (int*)alloc(1024 * 4);
    float* isd       = (float*)alloc(NN * 4);
    int*   csr_src   = (int*)alloc((size_t)EE * 4);
    float* csr_w     = (float*)alloc((size_t)EE * 4);

    // GNN stage overlays hidden (dead after kv GEMM): 3 buffers of NP rows
    const size_t NPE = (size_t)NP * 256;
    u16* gZ0 = hidden;            // hb -> x2
    u16* gZ1 = hidden + NPE;      // x1 -> h2
    u16* gZ2 = hidden + 2 * NPE;  // h1 -> thid

    const int* esrc = edge;
    const int* edst = edge + EE;

    auto wtp = [&](const float* W, int ld, int coloff, int fi, int Kpad, u16* Wt) {
        wtpose_k<<<(256 * Kpad + 255) / 256, 256, 0, stream>>>(W, ld, coloff, fi, Kpad, Wt);
    };

    // ---- CSR prep ----
    hipMemsetAsync(cnt, 0, NN * 4, stream);
    hipMemsetAsync(cursor, 0, NN * 4, stream);
    edge_count_k<<<(EE + 255) / 256, 256, 0, stream>>>(edst, cnt, EE);
    isd_k<<<(NN + 255) / 256, 256, 0, stream>>>(cnt, isd, NN);
    int nb = (NN + SCANB - 1) / SCANB;
    scan1_k<<<nb, SCANB, 0, stream>>>(cnt, row_start, bsums, NN);
    scan2_k<<<1, 64, 0, stream>>>(bsums, nb);
    scan3_k<<<nb, SCANB, 0, stream>>>(row_start, bsums, NN, EE);
    csr_scatter_k<<<(EE + 255) / 256, 256, 0, stream>>>(esrc, edst, row_start, cursor, isd,
                                                        csr_src, csr_w, EE);

    // ---- weight prep ----
    wtp(rp_W1, 256, 0, 256, 256, wt_rp1);                    // z-part only; extras in epilogue
    wfuse_k<<<256, 256, 0, stream>>>(rp_W2, inW, 768, 256, rp_b2, inB + 256, wt_kv, bias_kv);
    wfuse_k<<<256, 256, 0, stream>>>(rp_W2, inW, 768, 512, rp_b2, inB + 512,
                                     wt_kv + 256 * 256, bias_kv + 256);
    wfuse_k<<<256, 256, 0, stream>>>(qp_W, inW, 768, 0, qp_b, inB, wt_qf, bias_qf);
    wtp(outW, 256, 0, 256, 256, wt_o);
    wtp(gW1,  256, 0, 512, 512, wt_g1);
    wtp(gW2,  256, 0, 256, 256, wt_g2);
    wtp(uW1,  256, 0, 256, 256, wt_u1);
    wtp(uW2,  256, 0, 256, 256, wt_u2);
    wtp(gnW1, 256, 0, 256, 256, wt_gn1);
    wtp(gnW2, 256, 0, 256, 256, wt_gn2);
    wtp(hW1,  256, 0, 256, 256, wt_h1);
    gather_hq_k<<<(KKP + 3) / 4, 256, 0, stream>>>(h_cone, nids, acat);

    // ---- retrieval MLP layer 1 (fp32 A, retr extras in epilogue) ----
    gemm_bf_k<1, 1, 1, 1><<<dim3(KRR / 128, 2), 256, 0, stream>>>(
        z_retr, 256, KRR, 256, wt_rp1, rp_b1, hidden, 256,
        o_retr, retr_score, rp_W1 + 256 * 256);
    // ---- fused K|V projection: khv = hidden @ [W2@Wk | W2@Wv] ----
    gemm_bf_k<0, 1, 0, 0><<<dim3(KRR / 128, 4), 256, 0, stream>>>(
        hidden, 256, KRR, 256, wt_kv, bias_kv, khv, 512, nullptr, nullptr, nullptr);
    // ---- fused query projection ----
    gemm_bf_k<0, 1, 0, 0><<<dim3((KKP + 127) / 128, 2), 256, 0, stream>>>(
        acat, 512, KKP, 256, wt_qf, bias_qf, qhb, 256, nullptr, nullptr, nullptr);

    // ---- attention (fused scores+softmax+apply) ----
    att_fused_k<<<KKP, 256, 0, stream>>>(qhb, khv, ctxb);
    gemm_bf_k<0, 1, 0, 0><<<dim3((KKP + 127) / 128, 2), 256, 0, stream>>>(
        ctxb, 256, KKP, 256, wt_o, outB, acat + 256, 512, nullptr, nullptr, nullptr);

    // ---- gate / update ----
    gemm_bf_k<1, 1, 0, 0><<<dim3((KKP + 127) / 128, 2), 256, 0, stream>>>(
        acat, 512, KKP, 512, wt_g1, gB1, ghid, 256, nullptr, nullptr, nullptr);
    gemm_bf_k<2, 2, 0, 0><<<dim3((KKP + 127) / 128, 2), 256, 0, stream>>>(
        ghid, 256, KKP, 256, wt_g2, gB2, gate, 256, nullptr, nullptr, nullptr);
    gemm_bf_k<1, 1, 0, 0><<<dim3((KKP + 127) / 128, 2), 256, 0, stream>>>(
        acat + 256, 512, KKP, 256, wt_u1, uB1, uhid, 256, nullptr, nullptr, nullptr);
    gemm_bf_k<0, 2, 0, 0><<<dim3((KKP + 127) / 128, 2), 256, 0, stream>>>(
        uhid, 256, KKP, 256, wt_u2, uB2, upd, 256, nullptr, nullptr, nullptr);

    // ---- scatter into hb (bf16 copy of h_cone, winner rows overwritten) ----
    conv_f2b_k<<<(int)(((size_t)NN * 64 + 255) / 256), 256, 0, stream>>>(
        h_cone, gZ0, (size_t)NN * 64);
    hipMemsetAsync(winner, 0xFF, NN * 4, stream);
    winner_k<<<(KKP + 255) / 256, 256, 0, stream>>>(nids, winner);
    scatter_h_k<<<(KKP + 3) / 4, 256, 0, stream>>>(nids, winner, h_cone, gate, upd, gZ0);

    // ---- cone GNN ----
    gemm_bf_k<0, 1, 0, 0><<<dim3((NN + 127) / 128, 2), 256, 0, stream>>>(
        gZ0, 256, NN, 256, wt_gn1, gnB1, gZ1, 256, nullptr, nullptr, nullptr);       // x1
    gnn_agg_k<1><<<(NN + 3) / 4, 256, 0, stream>>>(gZ1, row_start, csr_src, csr_w, isd, gZ2); // h1
    gemm_bf_k<0, 1, 0, 0><<<dim3((NN + 127) / 128, 2), 256, 0, stream>>>(
        gZ2, 256, NN, 256, wt_gn2, gnB2, gZ0, 256, nullptr, nullptr, nullptr);       // x2
    gnn_agg_k<0><<<(NN + 3) / 4, 256, 0, stream>>>(gZ0, row_start, csr_src, csr_w, isd, gZ1); // h2
    gemm_bf_k<1, 1, 0, 0><<<dim3((NN + 127) / 128, 2), 256, 0, stream>>>(
        gZ1, 256, NN, 256, wt_h1, hB1, gZ2, 256, nullptr, nullptr, nullptr);         // thid
    head_out_k<<<(NN + 31) / 32, 256, 0, stream>>>(gZ2, hW2, hB2, teacher, out, NN);
}